// Round 2
// 580.795 us; speedup vs baseline: 1.2508x; 1.2508x over previous
//
#include <hip/hip_runtime.h>

#define S_LEN 2048
#define DMODEL 4096
#define NQKV 6144   // 32*128 + 8*128 + 8*128

typedef unsigned short u16;
typedef __attribute__((ext_vector_type(8))) short bf16x8;
typedef __attribute__((ext_vector_type(8))) unsigned short u16x8;
typedef __attribute__((ext_vector_type(4))) float f32x4;

#define NEG_BIG (-3.0e38f)

__device__ __forceinline__ float bf2f(u16 h) {
    union { unsigned u; float f; } c; c.u = ((unsigned)h) << 16; return c.f;
}
__device__ __forceinline__ u16 f2bf(float x) {
    union { float f; unsigned u; } c; c.f = x;
    return (u16)((c.u + 0x7fffu + ((c.u >> 16) & 1u)) >> 16);
}

// async global->LDS, 16B per lane; LDS dest = wave-uniform base + lane*16
__device__ __forceinline__ void gload16(const void* g, void* l) {
    __builtin_amdgcn_global_load_lds(
        (const __attribute__((address_space(1))) void*)g,
        (__attribute__((address_space(3))) void*)l, 16, 0, 0);
}

// ------------- dtype probe: flag[0]=1 if `probe` is fp32-underlying ------------
__global__ __launch_bounds__(256) void detect_dtype(const u16* __restrict__ probe,
                                                    int* __restrict__ flags) {
    __shared__ int bad_s;
    if (threadIdx.x == 0) bad_s = 0;
    __syncthreads();
    int bad = 0;
    for (int i = threadIdx.x; i < 16384; i += 256) {
        float v = bf2f(probe[i]);
        if (!(fabsf(v) < 1e6f)) bad = 1;   // catches NaN too
    }
    if (bad) atomicOr(&bad_s, 1);
    __syncthreads();
    if (threadIdx.x == 0) { flags[0] = bad_s; flags[1] = 0; }
}

// ------------- convert (fp32 or bf16) -> bf16, flat ----------------------------
__global__ __launch_bounds__(256) void conv_bf16(const void* __restrict__ src,
                                                 u16* __restrict__ dst, long n,
                                                 const int* __restrict__ flag) {
    const bool f32 = (*flag != 0);
    long i = (long)blockIdx.x * 256 + threadIdx.x;
    long stride = (long)gridDim.x * 256;
    for (; i < n; i += stride) {
        float v = f32 ? ((const float*)src)[i] : bf2f(((const u16*)src)[i]);
        dst[i] = f2bf(v);
    }
}

// ------------- transpose (fp32-or-bf16 in, bf16 out): dst[c][r] = src[r][c] ----
__global__ __launch_bounds__(256) void transpose_any(
        const void* __restrict__ src, long base_off, long sld, long szoff,
        u16* __restrict__ dst, long dld, long dzoff,
        const int* __restrict__ flag) {
    __shared__ alignas(16) u16 tile[32][33];
    const bool f32 = (*flag != 0);
    u16* d = dst + (long)blockIdx.z * dzoff;
    long soff = base_off + (long)blockIdx.z * szoff;
    int c0 = blockIdx.x * 32, r0 = blockIdx.y * 32;
    int tx = threadIdx.x & 31, ty = threadIdx.x >> 5;   // 32x8
    for (int i = 0; i < 32; i += 8) {
        long idx = soff + (long)(r0 + ty + i) * sld + c0 + tx;
        float v = f32 ? ((const float*)src)[idx] : bf2f(((const u16*)src)[idx]);
        tile[ty + i][tx] = f2bf(v);
    }
    __syncthreads();
    for (int i = 0; i < 32; i += 8)
        d[(long)(c0 + ty + i) * dld + r0 + tx] = tile[tx][ty + i];
}

// ---------------- GEMM: C[m][n] = sum_k A[m][k] * BT[n][k], bf16 in/out --------
// staging via global_load_lds width=16 (m151: +35% vs reg-staging at this tile)
__global__ __launch_bounds__(256, 2) void gemm_bt(
        const u16* __restrict__ A, const u16* __restrict__ BT,
        u16* __restrict__ C, int K, int ldc) {
    __shared__ alignas(16) u16 Asm[128 * 64];
    __shared__ alignas(16) u16 Bsm[128 * 64];
    const int tid = threadIdx.x;
    const int lane = tid & 63, wid = tid >> 6;
    const int wm = wid >> 1, wn = wid & 1;           // 2x2 waves, 64x64 each
    const int lm = lane & 15, lq = lane >> 4;
    const int m0 = blockIdx.y * 128, n0 = blockIdx.x * 128;

    f32x4 acc[4][4] = {};
    const int nk = K >> 6;
    for (int kt = 0; kt < nk; ++kt) {
        const int k0 = kt << 6;
        __syncthreads();
        for (int i = 0; i < 4; ++i) {
            int g = i * 256 + tid;
            int r = g >> 3, kg = g & 7;
            gload16(A  + (size_t)(m0 + r) * K + k0 + kg * 8,
                    Asm + (size_t)(i * 256 + wid * 64) * 8);
            gload16(BT + (size_t)(n0 + r) * K + k0 + kg * 8,
                    Bsm + (size_t)(i * 256 + wid * 64) * 8);
        }
        __syncthreads();
        for (int ks = 0; ks < 2; ++ks) {
            bf16x8 af[4], bfr[4];
            for (int i = 0; i < 4; ++i)
                af[i] = *(const bf16x8*)(const void*)(Asm + (wm * 64 + i * 16 + lm) * 64 + ks * 32 + lq * 8);
            for (int i = 0; i < 4; ++i)
                bfr[i] = *(const bf16x8*)(const void*)(Bsm + (wn * 64 + i * 16 + lm) * 64 + ks * 32 + lq * 8);
            for (int mi = 0; mi < 4; ++mi)
                for (int ni = 0; ni < 4; ++ni)
                    acc[mi][ni] = __builtin_amdgcn_mfma_f32_16x16x32_bf16(af[mi], bfr[ni], acc[mi][ni], 0, 0, 0);
        }
    }
    for (int mi = 0; mi < 4; ++mi)
        for (int ni = 0; ni < 4; ++ni) {
            int col = n0 + wn * 64 + ni * 16 + lm;
            int rowb = m0 + wm * 64 + mi * 16 + lq * 4;
            for (int r = 0; r < 4; ++r)
                C[(size_t)(rowb + r) * ldc + col] = f2bf(acc[mi][ni][r]);
        }
}

// ---------------- same GEMM, fp32 output (for d_out) ---------------------------
__global__ __launch_bounds__(256, 2) void gemm_bt_f32(
        const u16* __restrict__ A, const u16* __restrict__ BT,
        float* __restrict__ C, int K, int ldc) {
    __shared__ alignas(16) u16 Asm[128 * 64];
    __shared__ alignas(16) u16 Bsm[128 * 64];
    const int tid = threadIdx.x;
    const int lane = tid & 63, wid = tid >> 6;
    const int wm = wid >> 1, wn = wid & 1;
    const int lm = lane & 15, lq = lane >> 4;
    const int m0 = blockIdx.y * 128, n0 = blockIdx.x * 128;

    f32x4 acc[4][4] = {};
    const int nk = K >> 6;
    for (int kt = 0; kt < nk; ++kt) {
        const int k0 = kt << 6;
        __syncthreads();
        for (int i = 0; i < 4; ++i) {
            int g = i * 256 + tid;
            int r = g >> 3, kg = g & 7;
            gload16(A  + (size_t)(m0 + r) * K + k0 + kg * 8,
                    Asm + (size_t)(i * 256 + wid * 64) * 8);
            gload16(BT + (size_t)(n0 + r) * K + k0 + kg * 8,
                    Bsm + (size_t)(i * 256 + wid * 64) * 8);
        }
        __syncthreads();
        for (int ks = 0; ks < 2; ++ks) {
            bf16x8 af[4], bfr[4];
            for (int i = 0; i < 4; ++i)
                af[i] = *(const bf16x8*)(const void*)(Asm + (wm * 64 + i * 16 + lm) * 64 + ks * 32 + lq * 8);
            for (int i = 0; i < 4; ++i)
                bfr[i] = *(const bf16x8*)(const void*)(Bsm + (wn * 64 + i * 16 + lm) * 64 + ks * 32 + lq * 8);
            for (int mi = 0; mi < 4; ++mi)
                for (int ni = 0; ni < 4; ++ni)
                    acc[mi][ni] = __builtin_amdgcn_mfma_f32_16x16x32_bf16(af[mi], bfr[ni], acc[mi][ni], 0, 0, 0);
        }
    }
    for (int mi = 0; mi < 4; ++mi)
        for (int ni = 0; ni < 4; ++ni) {
            int col = n0 + wn * 64 + ni * 16 + lm;
            int rowb = m0 + wm * 64 + mi * 16 + lq * 4;
            for (int r = 0; r < 4; ++r)
                C[(size_t)(rowb + r) * ldc + col] = acc[mi][ni][r];   // fp32 out
        }
}

// ---------------- RMSNorm + RoPE on q (32 heads) and k (8 heads) ---------------
// NOTE: folds 1/sqrt(128) attention scale into Q (linear, commutes with RoPE)
__global__ __launch_bounds__(256) void rms_rope(
        const u16* __restrict__ qkv, const int* __restrict__ pos,
        const u16* __restrict__ qs, const u16* __restrict__ kscale,
        u16* __restrict__ Qb, u16* __restrict__ Kb) {
    int w = threadIdx.x >> 6, lane = threadIdx.x & 63;
    int task = blockIdx.x * 4 + w;            // task = h*2048 + row, h in [0,40)
    int h = task >> 11, row = task & 2047;
    int base = (h < 32) ? h * 128 : 4096 + (h - 32) * 128;
    const u16* src = qkv + (size_t)row * NQKV + base;
    float t0 = bf2f(src[lane]), t1 = bf2f(src[lane + 64]);
    float ss = t0 * t0 + t1 * t1;
    for (int m = 1; m < 64; m <<= 1) ss += __shfl_xor(ss, m);
    float inv = rsqrtf(ss * (1.0f / 128.0f) + 1e-6f);
    const u16* sc = (h < 32) ? qs : kscale;
    float n0 = t0 * inv * bf2f(sc[lane]);
    float n1 = t1 * inv * bf2f(sc[lane + 64]);
    float p = (float)pos[row];
    float ang = p * __expf(-(float)lane * (9.210340371976184f / 64.0f));  // 10000^(-lane/64)
    float c = cosf(ang), s = sinf(ang);
    float o0 = n0 * c - n1 * s;
    float o1 = n1 * c + n0 * s;
    float mul = (h < 32) ? 0.08838834764831845f : 1.0f;   // 1/sqrt(128) folded into Q
    u16* dst = (h < 32) ? (Qb + ((size_t)h * S_LEN + row) * 128)
                        : (Kb + ((size_t)(h - 32) * S_LEN + row) * 128);
    dst[lane] = f2bf(o0 * mul);
    dst[lane + 64] = f2bf(o1 * mul);
}

// ---------------- flash attention v2: 64-row Q tiles, paired for balance -------
// block x in [0,16) handles Q-tiles t=x and t=31-x  => exactly 33 KV-iters/block
// K/V/Q staged via global_load_lds (linear dest) with inverse-swizzled global
// source; all LDS reads XOR-swizzled:  u16_idx ^= (row&7)<<3   (T2, m201 pattern)
__global__ __launch_bounds__(256, 2) void flash_attn(
        const u16* __restrict__ Qb, const u16* __restrict__ Kb,
        const u16* __restrict__ VTb, u16* __restrict__ ctx) {
    const int h = blockIdx.y, kvh = h >> 2;
    const int tid = threadIdx.x, lane = tid & 63, w = tid >> 6;
    const int lm = lane & 15, lq = lane >> 4;
    const int swz = (lm & 7) << 3;                 // read-side XOR (u16 units)
    __shared__ alignas(16) u16 smem[20480];        // 40 KB
    u16* Ksm = smem;            // [64][128] swizzled (also Q staging area)
    u16* Vsm = smem + 8192;     // [128][64] swizzled (V^T tile)
    u16* Psm = smem + 16384;    // [64][64]  swizzled
    const u16* Kh = Kb + (size_t)kvh * S_LEN * 128;
    const u16* Vh = VTb + (size_t)kvh * 128 * S_LEN;

    for (int pass = 0; pass < 2; ++pass) {
        const int t = pass ? (31 - blockIdx.x) : blockIdx.x;
        const u16* Qh = Qb + ((size_t)h * S_LEN + (size_t)t * 64) * 128;

        __syncthreads();   // protect LDS reuse across passes
        // ---- stage 64x128 Q tile (swizzled) into Ksm ----
        for (int i = 0; i < 4; ++i) {
            int g = i * 256 + tid;
            int row = g >> 4, s = g & 15;
            int sp = (s & 8) | ((s ^ row) & 7);    // inverse swizzle on source
            gload16(Qh + (size_t)row * 128 + sp * 8,
                    Ksm + (size_t)(i * 256 + w * 64) * 8);
        }
        __syncthreads();
        bf16x8 aq[4];
        for (int ks = 0; ks < 4; ++ks)
            aq[ks] = *(const bf16x8*)(const void*)(
                Ksm + (((w * 16 + lm) * 128 + ks * 32 + lq * 8) ^ swz));

        float mrow[4], lrow[4];
        f32x4 accO[8];
        const f32x4 zero = {0.f, 0.f, 0.f, 0.f};
        for (int r = 0; r < 4; ++r) { mrow[r] = NEG_BIG; lrow[r] = 0.f; }
        for (int di = 0; di < 8; ++di) accO[di] = zero;

        for (int j = 0; j <= t; ++j) {
            __syncthreads();   // prev PV reads / aq loads done
            // ---- stage K tile [64][128] ----
            for (int i = 0; i < 4; ++i) {
                int g = i * 256 + tid;
                int row = g >> 4, s = g & 15;
                int sp = (s & 8) | ((s ^ row) & 7);
                gload16(Kh + (size_t)(j * 64 + row) * 128 + sp * 8,
                        Ksm + (size_t)(i * 256 + w * 64) * 8);
            }
            // ---- stage V^T tile [128][64] ----
            for (int i = 0; i < 4; ++i) {
                int g = i * 256 + tid;
                int d = g >> 3, s = g & 7;
                int sp = s ^ (d & 7);
                gload16(Vh + (size_t)d * S_LEN + j * 64 + sp * 8,
                        Vsm + (size_t)(i * 256 + w * 64) * 8);
            }
            __syncthreads();

            // ---- QK^T: 16 rows x 64 cols per wave ----
            f32x4 sacc[4] = {};
            for (int ks = 0; ks < 4; ++ks) {
                bf16x8 kf[4];
                for (int ni = 0; ni < 4; ++ni)
                    kf[ni] = *(const bf16x8*)(const void*)(
                        Ksm + (((ni * 16 + lm) * 128 + ks * 32 + lq * 8) ^ swz));
                for (int ni = 0; ni < 4; ++ni)
                    sacc[ni] = __builtin_amdgcn_mfma_f32_16x16x32_bf16(aq[ks], kf[ni], sacc[ni], 0, 0, 0);
            }

            // ---- causal mask: only the diagonal tile needs it ----
            if (j == t) {
                for (int ni = 0; ni < 4; ++ni) {
                    int col = ni * 16 + lm;
                    for (int r = 0; r < 4; ++r)
                        if (col > w * 16 + lq * 4 + r) sacc[ni][r] = NEG_BIG;
                }
            }

            // ---- online softmax (scale already folded into Q) ----
            for (int r = 0; r < 4; ++r) {
                float mx = fmaxf(fmaxf(sacc[0][r], sacc[1][r]),
                                 fmaxf(sacc[2][r], sacc[3][r]));
                for (int sft = 1; sft < 16; sft <<= 1) mx = fmaxf(mx, __shfl_xor(mx, sft));
                float mN = fmaxf(mrow[r], mx);
                float alpha = __expf(mrow[r] - mN);
                mrow[r] = mN;
                float psum = 0.f;
                int prow = w * 16 + lq * 4 + r;
                for (int ni = 0; ni < 4; ++ni) {
                    float pv = __expf(sacc[ni][r] - mN);
                    psum += pv;
                    Psm[prow * 64 + ((ni * 16 + lm) ^ ((prow & 7) << 3))] = f2bf(pv);
                }
                for (int sft = 1; sft < 16; sft <<= 1) psum += __shfl_xor(psum, sft);
                lrow[r] = lrow[r] * alpha + psum;
                for (int di = 0; di < 8; ++di) accO[di][r] *= alpha;
            }
            __syncthreads();

            // ---- PV: P(16x64) @ V(64x128) per wave ----
            for (int ks2 = 0; ks2 < 2; ++ks2) {
                bf16x8 pf = *(const bf16x8*)(const void*)(
                    Psm + (((w * 16 + lm) * 64 + ks2 * 32 + lq * 8) ^ swz));
                for (int di = 0; di < 8; ++di) {
                    bf16x8 vf = *(const bf16x8*)(const void*)(
                        Vsm + (((di * 16 + lm) * 64 + ks2 * 32 + lq * 8) ^ swz));
                    accO[di] = __builtin_amdgcn_mfma_f32_16x16x32_bf16(pf, vf, accO[di], 0, 0, 0);
                }
            }
        }

        // ---- epilogue ----
        for (int r = 0; r < 4; ++r) {
            float invl = 1.0f / fmaxf(lrow[r], 1e-30f);
            size_t rowg = (size_t)t * 64 + w * 16 + lq * 4 + r;
            for (int di = 0; di < 8; ++di)
                ctx[rowg * 4096 + h * 128 + di * 16 + lm] = f2bf(accO[di][r] * invl);
        }
    }
}

extern "C" void kernel_launch(void* const* d_in, const int* in_sizes, int n_in,
                              void* d_out, int out_size, void* d_ws, size_t ws_size,
                              hipStream_t stream) {
    const void* x   = d_in[0];
    const int* pos  = (const int*)d_in[1];
    const void* Wq  = d_in[2];
    const void* Wk  = d_in[3];
    const void* Wv  = d_in[4];
    const void* Wo  = d_in[5];
    const void* qs  = d_in[6];
    const void* ks  = d_in[7];

    if (ws_size < (size_t)145 * 1024 * 1024) return;
    char* ws = (char*)d_ws;
    u16* WqkvT = (u16*)ws;                                  // [6144][4096]   48 MiB
    u16* WoT   = (u16*)(ws + (size_t)48  * 1024 * 1024);    // [4096][4096]   32 MiB
    u16* qkv   = (u16*)(ws + (size_t)80  * 1024 * 1024);    // [2048][6144]   24 MiB
    u16* ctx   = qkv;                                       // aliases qkv (dead after VT/rms)
    u16* Qb    = (u16*)(ws + (size_t)104 * 1024 * 1024);    // [32][2048][128] 16 MiB
    u16* Kb    = (u16*)(ws + (size_t)120 * 1024 * 1024);    // [8][2048][128]   4 MiB
    u16* VTb   = (u16*)(ws + (size_t)124 * 1024 * 1024);    // [8][128][2048]   4 MiB
    u16* xb    = (u16*)(ws + (size_t)128 * 1024 * 1024);    // [2048][4096]    16 MiB
    int* flags = (int*)(ws + (size_t)144 * 1024 * 1024);
    u16* qsb   = (u16*)(ws + (size_t)144 * 1024 * 1024 + 1024);
    u16* ksb   = (u16*)(ws + (size_t)144 * 1024 * 1024 + 2048);

    dim3 b256(256);
    const int* flag  = flags;       // probed dtype
    const int* fzero = flags + 1;   // always 0

    detect_dtype<<<1, b256, 0, stream>>>((const u16*)Wq, flags);
    conv_bf16<<<8192, b256, 0, stream>>>(x,  xb,  (long)S_LEN * DMODEL, flag);
    conv_bf16<<<1,    b256, 0, stream>>>(qs, qsb, 128, flag);
    conv_bf16<<<1,    b256, 0, stream>>>(ks, ksb, 128, flag);

    // weight transposes into k-contiguous B^T layouts (bf16 out)
    transpose_any<<<dim3(128, 128, 1), b256, 0, stream>>>(Wq, 0, 4096, 0, WqkvT, 4096, 0, flag);
    transpose_any<<<dim3(32, 128, 1),  b256, 0, stream>>>(Wk, 0, 1024, 0, WqkvT + (size_t)4096 * 4096, 4096, 0, flag);
    transpose_any<<<dim3(32, 128, 1),  b256, 0, stream>>>(Wv, 0, 1024, 0, WqkvT + (size_t)5120 * 4096, 4096, 0, flag);
    transpose_any<<<dim3(128, 128, 1), b256, 0, stream>>>(Wo, 0, 4096, 0, WoT, 4096, 0, flag);

    // fused QKV projection: [2048][6144] bf16
    gemm_bt<<<dim3(48, 16), b256, 0, stream>>>(xb, WqkvT, qkv, 4096, NQKV);
    // RMSNorm + RoPE -> head-major Q (pre-scaled by 1/sqrt(128)) / K
    rms_rope<<<dim3(20480), b256, 0, stream>>>(qkv, pos, qsb, ksb, Qb, Kb);
    // V -> V^T per kv head ([8][128][2048]); qkv is bf16 -> force bf16 path
    transpose_any<<<dim3(4, 64, 8), b256, 0, stream>>>(qkv, 5120, NQKV, 128, VTb, 2048, (long)128 * 2048, fzero);
    // causal GQA flash attention: paired 64-row Q tiles -> ctx [2048][4096]
    flash_attn<<<dim3(16, 32), b256, 0, stream>>>(Qb, Kb, VTb, ctx);
    // output projection -> d_out as FP32 (reference output dtype is float32)
    gemm_bt_f32<<<dim3(32, 16), b256, 0, stream>>>(ctx, WoT, (float*)d_out, 4096, 4096);
}

// Round 3
// 573.047 us; speedup vs baseline: 1.2677x; 1.0135x over previous
//
#include <hip/hip_runtime.h>

#define S_LEN 2048
#define DMODEL 4096
#define NQKV 6144   // 32*128 + 8*128 + 8*128

typedef unsigned short u16;
typedef __attribute__((ext_vector_type(8))) short bf16x8;
typedef __attribute__((ext_vector_type(8))) unsigned short u16x8;
typedef __attribute__((ext_vector_type(4))) float f32x4;

#define NEG_BIG (-3.0e38f)

__device__ __forceinline__ float bf2f(u16 h) {
    union { unsigned u; float f; } c; c.u = ((unsigned)h) << 16; return c.f;
}
__device__ __forceinline__ u16 f2bf(float x) {
    union { float f; unsigned u; } c; c.f = x;
    return (u16)((c.u + 0x7fffu + ((c.u >> 16) & 1u)) >> 16);
}

// async global->LDS, 16B per lane; LDS dest = wave-uniform base + lane*16
__device__ __forceinline__ void gload16(const void* g, void* l) {
    __builtin_amdgcn_global_load_lds(
        (const __attribute__((address_space(1))) void*)g,
        (__attribute__((address_space(3))) void*)l, 16, 0, 0);
}

__device__ __forceinline__ void barfence() {
    asm volatile("" ::: "memory");
    __builtin_amdgcn_s_barrier();
    asm volatile("" ::: "memory");
}

// ------------- dtype probe: flag[0]=1 if `probe` is fp32-underlying ------------
__global__ __launch_bounds__(256) void detect_dtype(const u16* __restrict__ probe,
                                                    int* __restrict__ flags) {
    __shared__ int bad_s;
    if (threadIdx.x == 0) bad_s = 0;
    __syncthreads();
    int bad = 0;
    for (int i = threadIdx.x; i < 16384; i += 256) {
        float v = bf2f(probe[i]);
        if (!(fabsf(v) < 1e6f)) bad = 1;   // catches NaN too
    }
    if (bad) atomicOr(&bad_s, 1);
    __syncthreads();
    if (threadIdx.x == 0) { flags[0] = bad_s; flags[1] = 0; }
}

// ------------- convert (fp32 or bf16) -> bf16, flat ----------------------------
__global__ __launch_bounds__(256) void conv_bf16(const void* __restrict__ src,
                                                 u16* __restrict__ dst, long n,
                                                 const int* __restrict__ flag) {
    const bool f32 = (*flag != 0);
    long i = (long)blockIdx.x * 256 + threadIdx.x;
    long stride = (long)gridDim.x * 256;
    for (; i < n; i += stride) {
        float v = f32 ? ((const float*)src)[i] : bf2f(((const u16*)src)[i]);
        dst[i] = f2bf(v);
    }
}

// ------------- transpose (fp32-or-bf16 in, bf16 out): dst[c][r] = src[r][c] ----
__global__ __launch_bounds__(256) void transpose_any(
        const void* __restrict__ src, long base_off, long sld, long szoff,
        u16* __restrict__ dst, long dld, long dzoff,
        const int* __restrict__ flag) {
    __shared__ alignas(16) u16 tile[32][33];
    const bool f32 = (*flag != 0);
    u16* d = dst + (long)blockIdx.z * dzoff;
    long soff = base_off + (long)blockIdx.z * szoff;
    int c0 = blockIdx.x * 32, r0 = blockIdx.y * 32;
    int tx = threadIdx.x & 31, ty = threadIdx.x >> 5;   // 32x8
    for (int i = 0; i < 32; i += 8) {
        long idx = soff + (long)(r0 + ty + i) * sld + c0 + tx;
        float v = f32 ? ((const float*)src)[idx] : bf2f(((const u16*)src)[idx]);
        tile[ty + i][tx] = f2bf(v);
    }
    __syncthreads();
    for (int i = 0; i < 32; i += 8)
        d[(long)(c0 + ty + i) * dld + r0 + tx] = tile[tx][ty + i];
}

// ============== deep-pipelined GEMM: C[m][n] = sum_k A[m][k]*BT[n][k] ==========
// BM=256 BN=128 BK=32; 512 threads = 8 waves (4M x 2N), 64x64 out per wave.
// Quad-buffered LDS (96 KB), prefetch distance 3 tiles, counted vmcnt (T4),
// XOR-swizzled LDS (T2: colgrp ^= (row>>1)&3), setprio around MFMA (T5).
__device__ __forceinline__ void st_out(u16* C, size_t idx, float v)   { C[idx] = f2bf(v); }
__device__ __forceinline__ void st_out(float* C, size_t idx, float v) { C[idx] = v; }

template <typename OUT>
__device__ __forceinline__ void gemm_dp_core(
        const u16* __restrict__ A, const u16* __restrict__ BT,
        OUT* __restrict__ C, int K, int ldc) {
    // per buffer: A[256*32] u16 (8192) + B[128*32] u16 (4096) = 12288 u16 (24 KB)
    __shared__ alignas(16) u16 smem[4 * 12288];   // 96 KB
    const int tid = threadIdx.x;
    const int lane = tid & 63, wid = tid >> 6;
    const int wr = wid >> 1, wc = wid & 1;        // 4x2 waves
    const int lm = lane & 15, lq = lane >> 4;
    const int m0 = blockIdx.y * 256, n0 = blockIdx.x * 128;

    // ---- staging addresses (source pre-swizzled; LDS dest linear) ----
    const int cA0 = wid * 64 + lane;              // A chunk, ld=0 (0..511)
    const int cA1 = 512 + cA0;                    // A chunk, ld=1
    const int cB  = wid * 64 + lane;              // B chunk (0..511)
    const int rA0 = cA0 >> 2, rA1 = cA1 >> 2, rB = cB >> 2;
    const int spA0 = ((cA0 & 3) ^ ((rA0 >> 1) & 3)) * 8;
    const int spA1 = ((cA1 & 3) ^ ((rA1 >> 1) & 3)) * 8;
    const int spB  = ((cB  & 3) ^ ((rB  >> 1) & 3)) * 8;
    const u16* aS0 = A  + (size_t)(m0 + rA0) * K + spA0;
    const u16* aS1 = A  + (size_t)(m0 + rA1) * K + spA1;
    const u16* bS  = BT + (size_t)(n0 + rB ) * K + spB;
    const int ldsA0 = (wid * 64) * 8;             // wave-uniform LDS bases (u16)
    const int ldsA1 = (512 + wid * 64) * 8;
    const int ldsB  = 8192 + (wid * 64) * 8;

    const int NK = K >> 5;
    // ---- prologue: stage tiles 0,1,2 (9 loads/thread) ----
    for (int pt = 0; pt < 3; ++pt) {
        u16* buf = smem + pt * 12288;
        const int ko = pt << 5;
        gload16(aS0 + ko, buf + ldsA0);
        gload16(aS1 + ko, buf + ldsA1);
        gload16(bS  + ko, buf + ldsB);
    }
    asm volatile("s_waitcnt vmcnt(6)" ::: "memory");   // tile 0 landed
    barfence();

    f32x4 acc[4][4] = {};
    const int arow = wr * 64 + lm;
    const int brow = wc * 64 + lm;

#pragma unroll 4
    for (int kt = 0; kt < NK; ++kt) {
        const u16* Ab = smem + (kt & 3) * 12288;
        const u16* Bb = Ab + 8192;
        // ---- ds-reads (swizzled) + stage kt+3 ----
        bf16x8 bfv[4], afv[4];
        for (int ni = 0; ni < 4; ++ni) {
            int row = brow + ni * 16;
            bfv[ni] = *(const bf16x8*)(const void*)(Bb + row * 32 + ((lq ^ ((row >> 1) & 3)) << 3));
        }
        for (int mi = 0; mi < 4; ++mi) {
            int row = arow + mi * 16;
            afv[mi] = *(const bf16x8*)(const void*)(Ab + row * 32 + ((lq ^ ((row >> 1) & 3)) << 3));
        }
        if (kt + 3 < NK) {
            u16* nb = smem + ((kt + 3) & 3) * 12288;
            const int ko = (kt + 3) << 5;
            gload16(aS0 + ko, nb + ldsA0);
            gload16(aS1 + ko, nb + ldsA1);
            gload16(bS  + ko, nb + ldsB);
        }
        barfence();
        __builtin_amdgcn_s_setprio(1);
        for (int mi = 0; mi < 4; ++mi)
            for (int ni = 0; ni < 4; ++ni)
                acc[mi][ni] = __builtin_amdgcn_mfma_f32_16x16x32_bf16(afv[mi], bfv[ni], acc[mi][ni], 0, 0, 0);
        __builtin_amdgcn_s_setprio(0);
        // ---- tile-end counted wait: next tile's buffer fully landed ----
        if (kt + 3 < NK)       { asm volatile("s_waitcnt vmcnt(6)" ::: "memory"); }
        else if (kt + 2 < NK)  { asm volatile("s_waitcnt vmcnt(3)" ::: "memory"); }
        else if (kt + 1 < NK)  { asm volatile("s_waitcnt vmcnt(0)" ::: "memory"); }
        barfence();
    }

    // ---- epilogue ----
    for (int mi = 0; mi < 4; ++mi)
        for (int ni = 0; ni < 4; ++ni) {
            int col  = n0 + wc * 64 + ni * 16 + lm;
            int rowb = m0 + wr * 64 + mi * 16 + lq * 4;
            for (int r = 0; r < 4; ++r)
                st_out(C, (size_t)(rowb + r) * ldc + col, acc[mi][ni][r]);
        }
}

__global__ __launch_bounds__(512, 1) void gemm_dp_bf16(
        const u16* __restrict__ A, const u16* __restrict__ BT,
        u16* __restrict__ C, int K, int ldc) {
    gemm_dp_core<u16>(A, BT, C, K, ldc);
}
__global__ __launch_bounds__(512, 1) void gemm_dp_f32(
        const u16* __restrict__ A, const u16* __restrict__ BT,
        float* __restrict__ C, int K, int ldc) {
    gemm_dp_core<float>(A, BT, C, K, ldc);
}

// ---------------- RMSNorm + RoPE on q (32 heads) and k (8 heads) ---------------
// NOTE: folds 1/sqrt(128) attention scale into Q (linear, commutes with RoPE)
__global__ __launch_bounds__(256) void rms_rope(
        const u16* __restrict__ qkv, const int* __restrict__ pos,
        const u16* __restrict__ qs, const u16* __restrict__ kscale,
        u16* __restrict__ Qb, u16* __restrict__ Kb) {
    int w = threadIdx.x >> 6, lane = threadIdx.x & 63;
    int task = blockIdx.x * 4 + w;            // task = h*2048 + row, h in [0,40)
    int h = task >> 11, row = task & 2047;
    int base = (h < 32) ? h * 128 : 4096 + (h - 32) * 128;
    const u16* src = qkv + (size_t)row * NQKV + base;
    float t0 = bf2f(src[lane]), t1 = bf2f(src[lane + 64]);
    float ss = t0 * t0 + t1 * t1;
    for (int m = 1; m < 64; m <<= 1) ss += __shfl_xor(ss, m);
    float inv = rsqrtf(ss * (1.0f / 128.0f) + 1e-6f);
    const u16* sc = (h < 32) ? qs : kscale;
    float n0 = t0 * inv * bf2f(sc[lane]);
    float n1 = t1 * inv * bf2f(sc[lane + 64]);
    float p = (float)pos[row];
    float ang = p * __expf(-(float)lane * (9.210340371976184f / 64.0f));  // 10000^(-lane/64)
    float c = cosf(ang), s = sinf(ang);
    float o0 = n0 * c - n1 * s;
    float o1 = n1 * c + n0 * s;
    float mul = (h < 32) ? 0.08838834764831845f : 1.0f;   // 1/sqrt(128) folded into Q
    u16* dst = (h < 32) ? (Qb + ((size_t)h * S_LEN + row) * 128)
                        : (Kb + ((size_t)(h - 32) * S_LEN + row) * 128);
    dst[lane] = f2bf(o0 * mul);
    dst[lane + 64] = f2bf(o1 * mul);
}

// ---------------- flash attention v2: 64-row Q tiles, paired for balance -------
// block x in [0,16) handles Q-tiles t=x and t=31-x  => exactly 33 KV-iters/block
// K/V/Q staged via global_load_lds (linear dest) with inverse-swizzled global
// source; all LDS reads XOR-swizzled:  u16_idx ^= (row&7)<<3   (T2, m201 pattern)
__global__ __launch_bounds__(256, 2) void flash_attn(
        const u16* __restrict__ Qb, const u16* __restrict__ Kb,
        const u16* __restrict__ VTb, u16* __restrict__ ctx) {
    const int h = blockIdx.y, kvh = h >> 2;
    const int tid = threadIdx.x, lane = tid & 63, w = tid >> 6;
    const int lm = lane & 15, lq = lane >> 4;
    const int swz = (lm & 7) << 3;                 // read-side XOR (u16 units)
    __shared__ alignas(16) u16 smem[20480];        // 40 KB
    u16* Ksm = smem;            // [64][128] swizzled (also Q staging area)
    u16* Vsm = smem + 8192;     // [128][64] swizzled (V^T tile)
    u16* Psm = smem + 16384;    // [64][64]  swizzled
    const u16* Kh = Kb + (size_t)kvh * S_LEN * 128;
    const u16* Vh = VTb + (size_t)kvh * 128 * S_LEN;

    for (int pass = 0; pass < 2; ++pass) {
        const int t = pass ? (31 - blockIdx.x) : blockIdx.x;
        const u16* Qh = Qb + ((size_t)h * S_LEN + (size_t)t * 64) * 128;

        __syncthreads();   // protect LDS reuse across passes
        // ---- stage 64x128 Q tile (swizzled) into Ksm ----
        for (int i = 0; i < 4; ++i) {
            int g = i * 256 + tid;
            int row = g >> 4, s = g & 15;
            int sp = (s & 8) | ((s ^ row) & 7);    // inverse swizzle on source
            gload16(Qh + (size_t)row * 128 + sp * 8,
                    Ksm + (size_t)(i * 256 + w * 64) * 8);
        }
        __syncthreads();
        bf16x8 aq[4];
        for (int ks = 0; ks < 4; ++ks)
            aq[ks] = *(const bf16x8*)(const void*)(
                Ksm + (((w * 16 + lm) * 128 + ks * 32 + lq * 8) ^ swz));

        float mrow[4], lrow[4];
        f32x4 accO[8];
        const f32x4 zero = {0.f, 0.f, 0.f, 0.f};
        for (int r = 0; r < 4; ++r) { mrow[r] = NEG_BIG; lrow[r] = 0.f; }
        for (int di = 0; di < 8; ++di) accO[di] = zero;

        for (int j = 0; j <= t; ++j) {
            __syncthreads();   // prev PV reads / aq loads done
            // ---- stage K tile [64][128] ----
            for (int i = 0; i < 4; ++i) {
                int g = i * 256 + tid;
                int row = g >> 4, s = g & 15;
                int sp = (s & 8) | ((s ^ row) & 7);
                gload16(Kh + (size_t)(j * 64 + row) * 128 + sp * 8,
                        Ksm + (size_t)(i * 256 + w * 64) * 8);
            }
            // ---- stage V^T tile [128][64] ----
            for (int i = 0; i < 4; ++i) {
                int g = i * 256 + tid;
                int d = g >> 3, s = g & 7;
                int sp = s ^ (d & 7);
                gload16(Vh + (size_t)d * S_LEN + j * 64 + sp * 8,
                        Vsm + (size_t)(i * 256 + w * 64) * 8);
            }
            __syncthreads();

            // ---- QK^T: 16 rows x 64 cols per wave ----
            f32x4 sacc[4] = {};
            for (int ks = 0; ks < 4; ++ks) {
                bf16x8 kf[4];
                for (int ni = 0; ni < 4; ++ni)
                    kf[ni] = *(const bf16x8*)(const void*)(
                        Ksm + (((ni * 16 + lm) * 128 + ks * 32 + lq * 8) ^ swz));
                for (int ni = 0; ni < 4; ++ni)
                    sacc[ni] = __builtin_amdgcn_mfma_f32_16x16x32_bf16(aq[ks], kf[ni], sacc[ni], 0, 0, 0);
            }

            // ---- causal mask: only the diagonal tile needs it ----
            if (j == t) {
                for (int ni = 0; ni < 4; ++ni) {
                    int col = ni * 16 + lm;
                    for (int r = 0; r < 4; ++r)
                        if (col > w * 16 + lq * 4 + r) sacc[ni][r] = NEG_BIG;
                }
            }

            // ---- online softmax (scale already folded into Q) ----
            for (int r = 0; r < 4; ++r) {
                float mx = fmaxf(fmaxf(sacc[0][r], sacc[1][r]),
                                 fmaxf(sacc[2][r], sacc[3][r]));
                for (int sft = 1; sft < 16; sft <<= 1) mx = fmaxf(mx, __shfl_xor(mx, sft));
                float mN = fmaxf(mrow[r], mx);
                float alpha = __expf(mrow[r] - mN);
                mrow[r] = mN;
                float psum = 0.f;
                int prow = w * 16 + lq * 4 + r;
                for (int ni = 0; ni < 4; ++ni) {
                    float pv = __expf(sacc[ni][r] - mN);
                    psum += pv;
                    Psm[prow * 64 + ((ni * 16 + lm) ^ ((prow & 7) << 3))] = f2bf(pv);
                }
                for (int sft = 1; sft < 16; sft <<= 1) psum += __shfl_xor(psum, sft);
                lrow[r] = lrow[r] * alpha + psum;
                for (int di = 0; di < 8; ++di) accO[di][r] *= alpha;
            }
            __syncthreads();

            // ---- PV: P(16x64) @ V(64x128) per wave ----
            for (int ks2 = 0; ks2 < 2; ++ks2) {
                bf16x8 pf = *(const bf16x8*)(const void*)(
                    Psm + (((w * 16 + lm) * 64 + ks2 * 32 + lq * 8) ^ swz));
                for (int di = 0; di < 8; ++di) {
                    bf16x8 vf = *(const bf16x8*)(const void*)(
                        Vsm + (((di * 16 + lm) * 64 + ks2 * 32 + lq * 8) ^ swz));
                    accO[di] = __builtin_amdgcn_mfma_f32_16x16x32_bf16(pf, vf, accO[di], 0, 0, 0);
                }
            }
        }

        // ---- epilogue ----
        for (int r = 0; r < 4; ++r) {
            float invl = 1.0f / fmaxf(lrow[r], 1e-30f);
            size_t rowg = (size_t)t * 64 + w * 16 + lq * 4 + r;
            for (int di = 0; di < 8; ++di)
                ctx[rowg * 4096 + h * 128 + di * 16 + lm] = f2bf(accO[di][r] * invl);
        }
    }
}

extern "C" void kernel_launch(void* const* d_in, const int* in_sizes, int n_in,
                              void* d_out, int out_size, void* d_ws, size_t ws_size,
                              hipStream_t stream) {
    const void* x   = d_in[0];
    const int* pos  = (const int*)d_in[1];
    const void* Wq  = d_in[2];
    const void* Wk  = d_in[3];
    const void* Wv  = d_in[4];
    const void* Wo  = d_in[5];
    const void* qs  = d_in[6];
    const void* ks  = d_in[7];

    if (ws_size < (size_t)145 * 1024 * 1024) return;
    char* ws = (char*)d_ws;
    u16* WqkvT = (u16*)ws;                                  // [6144][4096]   48 MiB
    u16* WoT   = (u16*)(ws + (size_t)48  * 1024 * 1024);    // [4096][4096]   32 MiB
    u16* qkv   = (u16*)(ws + (size_t)80  * 1024 * 1024);    // [2048][6144]   24 MiB
    u16* ctx   = qkv;                                       // aliases qkv (dead after VT/rms)
    u16* Qb    = (u16*)(ws + (size_t)104 * 1024 * 1024);    // [32][2048][128] 16 MiB
    u16* Kb    = (u16*)(ws + (size_t)120 * 1024 * 1024);    // [8][2048][128]   4 MiB
    u16* VTb   = (u16*)(ws + (size_t)124 * 1024 * 1024);    // [8][128][2048]   4 MiB
    u16* xb    = (u16*)(ws + (size_t)128 * 1024 * 1024);    // [2048][4096]    16 MiB
    int* flags = (int*)(ws + (size_t)144 * 1024 * 1024);
    u16* qsb   = (u16*)(ws + (size_t)144 * 1024 * 1024 + 1024);
    u16* ksb   = (u16*)(ws + (size_t)144 * 1024 * 1024 + 2048);

    dim3 b256(256);
    const int* flag  = flags;       // probed dtype
    const int* fzero = flags + 1;   // always 0

    detect_dtype<<<1, b256, 0, stream>>>((const u16*)Wq, flags);
    conv_bf16<<<8192, b256, 0, stream>>>(x,  xb,  (long)S_LEN * DMODEL, flag);
    conv_bf16<<<1,    b256, 0, stream>>>(qs, qsb, 128, flag);
    conv_bf16<<<1,    b256, 0, stream>>>(ks, ksb, 128, flag);

    // weight transposes into k-contiguous B^T layouts (bf16 out)
    transpose_any<<<dim3(128, 128, 1), b256, 0, stream>>>(Wq, 0, 4096, 0, WqkvT, 4096, 0, flag);
    transpose_any<<<dim3(32, 128, 1),  b256, 0, stream>>>(Wk, 0, 1024, 0, WqkvT + (size_t)4096 * 4096, 4096, 0, flag);
    transpose_any<<<dim3(32, 128, 1),  b256, 0, stream>>>(Wv, 0, 1024, 0, WqkvT + (size_t)5120 * 4096, 4096, 0, flag);
    transpose_any<<<dim3(128, 128, 1), b256, 0, stream>>>(Wo, 0, 4096, 0, WoT, 4096, 0, flag);

    // fused QKV projection: [2048][6144] bf16 (deep-pipelined GEMM, 256x128 tiles)
    gemm_dp_bf16<<<dim3(48, 8), dim3(512), 0, stream>>>(xb, WqkvT, qkv, 4096, NQKV);
    // RMSNorm + RoPE -> head-major Q (pre-scaled by 1/sqrt(128)) / K
    rms_rope<<<dim3(20480), b256, 0, stream>>>(qkv, pos, qsb, ksb, Qb, Kb);
    // V -> V^T per kv head ([8][128][2048]); qkv is bf16 -> force bf16 path
    transpose_any<<<dim3(4, 64, 8), b256, 0, stream>>>(qkv, 5120, NQKV, 128, VTb, 2048, (long)128 * 2048, fzero);
    // causal GQA flash attention: paired 64-row Q tiles -> ctx [2048][4096]
    flash_attn<<<dim3(16, 32), b256, 0, stream>>>(Qb, Kb, VTb, ctx);
    // output projection -> d_out as FP32 (deep-pipelined GEMM, 256x128 tiles)
    gemm_dp_f32<<<dim3(32, 8), dim3(512), 0, stream>>>(ctx, WoT, (float*)d_out, 4096, 4096);
}

// Round 4
// 561.379 us; speedup vs baseline: 1.2940x; 1.0208x over previous
//
#include <hip/hip_runtime.h>

#define S_LEN 2048
#define DMODEL 4096
#define NQKV 6144   // 32*128 + 8*128 + 8*128

typedef unsigned short u16;
typedef __attribute__((ext_vector_type(8))) short bf16x8;
typedef __attribute__((ext_vector_type(8))) unsigned short u16x8;
typedef __attribute__((ext_vector_type(4))) float f32x4;

#define NEG_BIG (-3.0e38f)

__device__ __forceinline__ float bf2f(u16 h) {
    union { unsigned u; float f; } c; c.u = ((unsigned)h) << 16; return c.f;
}
__device__ __forceinline__ u16 f2bf(float x) {
    union { float f; unsigned u; } c; c.f = x;
    return (u16)((c.u + 0x7fffu + ((c.u >> 16) & 1u)) >> 16);
}

// async global->LDS, 16B per lane; LDS dest = wave-uniform base + lane*16
__device__ __forceinline__ void gload16(const void* g, void* l) {
    __builtin_amdgcn_global_load_lds(
        (const __attribute__((address_space(1))) void*)g,
        (__attribute__((address_space(3))) void*)l, 16, 0, 0);
}

__device__ __forceinline__ void barfence() {
    asm volatile("" ::: "memory");
    __builtin_amdgcn_s_barrier();
    asm volatile("" ::: "memory");
}

#define MFMA16(d, av, bv) d = __builtin_amdgcn_mfma_f32_16x16x32_bf16(av, bv, d, 0, 0, 0)

// ------------- dtype probe: flag[0]=1 if `probe` is fp32-underlying ------------
__global__ __launch_bounds__(256) void detect_dtype(const u16* __restrict__ probe,
                                                    int* __restrict__ flags) {
    __shared__ int bad_s;
    if (threadIdx.x == 0) bad_s = 0;
    __syncthreads();
    int bad = 0;
    for (int i = threadIdx.x; i < 16384; i += 256) {
        float v = bf2f(probe[i]);
        if (!(fabsf(v) < 1e6f)) bad = 1;   // catches NaN too
    }
    if (bad) atomicOr(&bad_s, 1);
    __syncthreads();
    if (threadIdx.x == 0) { flags[0] = bad_s; flags[1] = 0; }
}

// ------------- convert (fp32 or bf16) -> bf16, flat ----------------------------
__global__ __launch_bounds__(256) void conv_bf16(const void* __restrict__ src,
                                                 u16* __restrict__ dst, long n,
                                                 const int* __restrict__ flag) {
    const bool f32 = (*flag != 0);
    long i = (long)blockIdx.x * 256 + threadIdx.x;
    long stride = (long)gridDim.x * 256;
    for (; i < n; i += stride) {
        float v = f32 ? ((const float*)src)[i] : bf2f(((const u16*)src)[i]);
        dst[i] = f2bf(v);
    }
}

// ------------- transpose (fp32-or-bf16 in, bf16 out): dst[c][r] = src[r][c] ----
__global__ __launch_bounds__(256) void transpose_any(
        const void* __restrict__ src, long base_off, long sld, long szoff,
        u16* __restrict__ dst, long dld, long dzoff,
        const int* __restrict__ flag) {
    __shared__ alignas(16) u16 tile[32][33];
    const bool f32 = (*flag != 0);
    u16* d = dst + (long)blockIdx.z * dzoff;
    long soff = base_off + (long)blockIdx.z * szoff;
    int c0 = blockIdx.x * 32, r0 = blockIdx.y * 32;
    int tx = threadIdx.x & 31, ty = threadIdx.x >> 5;   // 32x8
    for (int i = 0; i < 32; i += 8) {
        long idx = soff + (long)(r0 + ty + i) * sld + c0 + tx;
        float v = f32 ? ((const float*)src)[idx] : bf2f(((const u16*)src)[idx]);
        tile[ty + i][tx] = f2bf(v);
    }
    __syncthreads();
    for (int i = 0; i < 32; i += 8)
        d[(long)(c0 + ty + i) * dld + r0 + tx] = tile[tx][ty + i];
}

// ======== 4-phase 256x256 GEMM (m201-class): C[m][n] = sum_k A[m][k]*BT[n][k] ==
// BK=64, 512 thr = 8 waves (2M x 4N), 128x64 out/wave, acc[8][4].
// LDS 128 KB dbuf-2. Per K-tile: 4 phases x 16 MFMA; chunk issue order
// B0,B1 | B2,B3 | A0,A2 | A1,A3  =>  waits vmcnt(2) @ph0, vmcnt(4) @ph2
// (never 0 in steady state: T4). Swizzle: LDS[row][g] = G[row][g^(row&7)] (T2).
__device__ __forceinline__ void st_out(u16* C, size_t idx, float v)   { C[idx] = f2bf(v); }
__device__ __forceinline__ void st_out(float* C, size_t idx, float v) { C[idx] = v; }

template <typename OUT>
__device__ __forceinline__ void gemm_dp2_core(
        const u16* __restrict__ A, const u16* __restrict__ BT,
        OUT* __restrict__ C, int K, int ldc) {
    __shared__ alignas(16) u16 smem[65536];   // 2 bufs x (A 256x64 + B 256x64) = 128 KB
    const int tid = threadIdx.x;
    const int lane = tid & 63, wid = tid >> 6;
    const int wr = wid >> 2, wc = wid & 3;        // 2M x 4N waves
    const int lm = lane & 15, lq = lane >> 4;
    const int m0 = blockIdx.y * 256, n0 = blockIdx.x * 256;

    // staging: chunk = 64 rows x 64 cols (one gload16/thread); source pre-swizzled
    const int srow = tid >> 3;                       // row within chunk
    const int sgrp = (tid & 7) ^ (srow & 7);         // swizzled 8-u16 group
    const u16* aS = A  + (size_t)(m0 + srow) * K + sgrp * 8;
    const u16* bS = BT + (size_t)(n0 + srow) * K + sgrp * 8;
    u16* ldsA = smem + tid * 8;                      // + buf*32768 + c*4096
    u16* ldsB = smem + 16384 + tid * 8;

    auto stA = [&](int bufi, int c, int kti) {
        gload16(aS + (size_t)c * 64 * K + (size_t)kti * 64, ldsA + bufi * 32768 + c * 4096);
    };
    auto stB = [&](int bufi, int c, int kti) {
        gload16(bS + (size_t)c * 64 * K + (size_t)kti * 64, ldsB + bufi * 32768 + c * 4096);
    };
    auto rdA = [&](const u16* buf, int mi, int ks) {
        int row = wr * 128 + mi * 16 + lm;
        return *(const bf16x8*)(const void*)(buf + row * 64 + (((ks * 4 + lq) ^ (row & 7)) << 3));
    };
    auto rdB = [&](const u16* buf, int ni, int ks) {
        int row = wc * 64 + ni * 16 + lm;
        return *(const bf16x8*)(const void*)(buf + 16384 + row * 64 + (((ks * 4 + lq) ^ (row & 7)) << 3));
    };

    const int NK = K >> 6;
    // prologue: tile 0, ledger order B0,B1,B2,B3,A0,A2,A1,A3
    stB(0, 0, 0); stB(0, 1, 0); stB(0, 2, 0); stB(0, 3, 0);
    stA(0, 0, 0); stA(0, 2, 0); stA(0, 1, 0); stA(0, 3, 0);

    f32x4 acc[8][4] = {};
    bf16x8 b[4][2], a[2][2];

#pragma unroll 2
    for (int kt = 0; kt < NK; ++kt) {
        const u16* buf = smem + (kt & 1) * 32768;
        const int nb = (kt & 1) ^ 1;
        const int kn = kt + 1;
        const bool more = kn < NK;

        // ---------- phase 0: B all + A quadrant 0 ----------
        asm volatile("s_waitcnt vmcnt(2)" ::: "memory");   // B0-3,A0,A2 landed
        barfence();
#pragma unroll
        for (int ni = 0; ni < 4; ++ni)
#pragma unroll
            for (int ks = 0; ks < 2; ++ks) b[ni][ks] = rdB(buf, ni, ks);
#pragma unroll
        for (int q = 0; q < 2; ++q)
#pragma unroll
            for (int ks = 0; ks < 2; ++ks) a[q][ks] = rdA(buf, q, ks);
        if (more) { stB(nb, 0, kn); stB(nb, 1, kn); }
        __builtin_amdgcn_s_setprio(1);
#pragma unroll
        for (int q = 0; q < 2; ++q)
#pragma unroll
            for (int ni = 0; ni < 4; ++ni)
#pragma unroll
                for (int ks = 0; ks < 2; ++ks) MFMA16(acc[q][ni], a[q][ks], b[ni][ks]);
        __builtin_amdgcn_s_setprio(0);

        // ---------- phase 1: A quadrant 1 (chunks A0/A2 still) ----------
#pragma unroll
        for (int q = 0; q < 2; ++q)
#pragma unroll
            for (int ks = 0; ks < 2; ++ks) a[q][ks] = rdA(buf, 2 + q, ks);
        if (more) { stB(nb, 2, kn); stB(nb, 3, kn); }
        __builtin_amdgcn_s_setprio(1);
#pragma unroll
        for (int q = 0; q < 2; ++q)
#pragma unroll
            for (int ni = 0; ni < 4; ++ni)
#pragma unroll
                for (int ks = 0; ks < 2; ++ks) MFMA16(acc[2 + q][ni], a[q][ks], b[ni][ks]);
        __builtin_amdgcn_s_setprio(0);

        // ---------- phase 2: A quadrant 2 (needs chunks A1,A3) ----------
        if (more) { asm volatile("s_waitcnt vmcnt(4)" ::: "memory"); }
        else      { asm volatile("s_waitcnt vmcnt(0)" ::: "memory"); }
        barfence();
#pragma unroll
        for (int q = 0; q < 2; ++q)
#pragma unroll
            for (int ks = 0; ks < 2; ++ks) a[q][ks] = rdA(buf, 4 + q, ks);
        if (more) { stA(nb, 0, kn); stA(nb, 2, kn); }
        __builtin_amdgcn_s_setprio(1);
#pragma unroll
        for (int q = 0; q < 2; ++q)
#pragma unroll
            for (int ni = 0; ni < 4; ++ni)
#pragma unroll
                for (int ks = 0; ks < 2; ++ks) MFMA16(acc[4 + q][ni], a[q][ks], b[ni][ks]);
        __builtin_amdgcn_s_setprio(0);

        // ---------- phase 3: A quadrant 3 ----------
#pragma unroll
        for (int q = 0; q < 2; ++q)
#pragma unroll
            for (int ks = 0; ks < 2; ++ks) a[q][ks] = rdA(buf, 6 + q, ks);
        if (more) { stA(nb, 1, kn); stA(nb, 3, kn); }
        __builtin_amdgcn_s_setprio(1);
#pragma unroll
        for (int q = 0; q < 2; ++q)
#pragma unroll
            for (int ni = 0; ni < 4; ++ni)
#pragma unroll
                for (int ks = 0; ks < 2; ++ks) MFMA16(acc[6 + q][ni], a[q][ks], b[ni][ks]);
        __builtin_amdgcn_s_setprio(0);
    }

    // ---- epilogue ----
#pragma unroll
    for (int mi = 0; mi < 8; ++mi)
#pragma unroll
        for (int ni = 0; ni < 4; ++ni) {
            int col  = n0 + wc * 64 + ni * 16 + lm;
            int rowb = m0 + wr * 128 + mi * 16 + lq * 4;
#pragma unroll
            for (int r = 0; r < 4; ++r)
                st_out(C, (size_t)(rowb + r) * ldc + col, acc[mi][ni][r]);
        }
}

__global__ __launch_bounds__(512, 2) void gemm_dp2_bf16(
        const u16* __restrict__ A, const u16* __restrict__ BT,
        u16* __restrict__ C, int K, int ldc) {
    gemm_dp2_core<u16>(A, BT, C, K, ldc);
}
__global__ __launch_bounds__(512, 2) void gemm_dp2_f32(
        const u16* __restrict__ A, const u16* __restrict__ BT,
        float* __restrict__ C, int K, int ldc) {
    gemm_dp2_core<float>(A, BT, C, K, ldc);
}

// ---------------- RMSNorm + RoPE on q (32 heads) and k (8 heads) ---------------
// NOTE: folds 1/sqrt(128) attention scale into Q (linear, commutes with RoPE)
__global__ __launch_bounds__(256) void rms_rope(
        const u16* __restrict__ qkv, const int* __restrict__ pos,
        const u16* __restrict__ qs, const u16* __restrict__ kscale,
        u16* __restrict__ Qb, u16* __restrict__ Kb) {
    int w = threadIdx.x >> 6, lane = threadIdx.x & 63;
    int task = blockIdx.x * 4 + w;            // task = h*2048 + row, h in [0,40)
    int h = task >> 11, row = task & 2047;
    int base = (h < 32) ? h * 128 : 4096 + (h - 32) * 128;
    const u16* src = qkv + (size_t)row * NQKV + base;
    float t0 = bf2f(src[lane]), t1 = bf2f(src[lane + 64]);
    float ss = t0 * t0 + t1 * t1;
    for (int m = 1; m < 64; m <<= 1) ss += __shfl_xor(ss, m);
    float inv = rsqrtf(ss * (1.0f / 128.0f) + 1e-6f);
    const u16* sc = (h < 32) ? qs : kscale;
    float n0 = t0 * inv * bf2f(sc[lane]);
    float n1 = t1 * inv * bf2f(sc[lane + 64]);
    float p = (float)pos[row];
    float ang = p * __expf(-(float)lane * (9.210340371976184f / 64.0f));  // 10000^(-lane/64)
    float c = cosf(ang), s = sinf(ang);
    float o0 = n0 * c - n1 * s;
    float o1 = n1 * c + n0 * s;
    float mul = (h < 32) ? 0.08838834764831845f : 1.0f;   // 1/sqrt(128) folded into Q
    u16* dst = (h < 32) ? (Qb + ((size_t)h * S_LEN + row) * 128)
                        : (Kb + ((size_t)(h - 32) * S_LEN + row) * 128);
    dst[lane] = f2bf(o0 * mul);
    dst[lane + 64] = f2bf(o1 * mul);
}

// ---------------- flash attention v2: 64-row Q tiles, paired for balance -------
// block x in [0,16) handles Q-tiles t=x and t=31-x  => exactly 33 KV-iters/block
// K/V/Q staged via global_load_lds (linear dest) with inverse-swizzled global
// source; all LDS reads XOR-swizzled:  u16_idx ^= (row&7)<<3   (T2, m201 pattern)
__global__ __launch_bounds__(256, 2) void flash_attn(
        const u16* __restrict__ Qb, const u16* __restrict__ Kb,
        const u16* __restrict__ VTb, u16* __restrict__ ctx) {
    const int h = blockIdx.y, kvh = h >> 2;
    const int tid = threadIdx.x, lane = tid & 63, w = tid >> 6;
    const int lm = lane & 15, lq = lane >> 4;
    const int swz = (lm & 7) << 3;                 // read-side XOR (u16 units)
    __shared__ alignas(16) u16 smem[20480];        // 40 KB
    u16* Ksm = smem;            // [64][128] swizzled (also Q staging area)
    u16* Vsm = smem + 8192;     // [128][64] swizzled (V^T tile)
    u16* Psm = smem + 16384;    // [64][64]  swizzled
    const u16* Kh = Kb + (size_t)kvh * S_LEN * 128;
    const u16* Vh = VTb + (size_t)kvh * 128 * S_LEN;

    for (int pass = 0; pass < 2; ++pass) {
        const int t = pass ? (31 - blockIdx.x) : blockIdx.x;
        const u16* Qh = Qb + ((size_t)h * S_LEN + (size_t)t * 64) * 128;

        __syncthreads();   // protect LDS reuse across passes
        // ---- stage 64x128 Q tile (swizzled) into Ksm ----
        for (int i = 0; i < 4; ++i) {
            int g = i * 256 + tid;
            int row = g >> 4, s = g & 15;
            int sp = (s & 8) | ((s ^ row) & 7);    // inverse swizzle on source
            gload16(Qh + (size_t)row * 128 + sp * 8,
                    Ksm + (size_t)(i * 256 + w * 64) * 8);
        }
        __syncthreads();
        bf16x8 aq[4];
        for (int ks = 0; ks < 4; ++ks)
            aq[ks] = *(const bf16x8*)(const void*)(
                Ksm + (((w * 16 + lm) * 128 + ks * 32 + lq * 8) ^ swz));

        float mrow[4], lrow[4];
        f32x4 accO[8];
        const f32x4 zero = {0.f, 0.f, 0.f, 0.f};
        for (int r = 0; r < 4; ++r) { mrow[r] = NEG_BIG; lrow[r] = 0.f; }
        for (int di = 0; di < 8; ++di) accO[di] = zero;

        for (int j = 0; j <= t; ++j) {
            __syncthreads();   // prev PV reads / aq loads done
            // ---- stage K tile [64][128] ----
            for (int i = 0; i < 4; ++i) {
                int g = i * 256 + tid;
                int row = g >> 4, s = g & 15;
                int sp = (s & 8) | ((s ^ row) & 7);
                gload16(Kh + (size_t)(j * 64 + row) * 128 + sp * 8,
                        Ksm + (size_t)(i * 256 + w * 64) * 8);
            }
            // ---- stage V^T tile [128][64] ----
            for (int i = 0; i < 4; ++i) {
                int g = i * 256 + tid;
                int d = g >> 3, s = g & 7;
                int sp = s ^ (d & 7);
                gload16(Vh + (size_t)d * S_LEN + j * 64 + sp * 8,
                        Vsm + (size_t)(i * 256 + w * 64) * 8);
            }
            __syncthreads();

            // ---- QK^T: 16 rows x 64 cols per wave ----
            f32x4 sacc[4] = {};
            for (int ks = 0; ks < 4; ++ks) {
                bf16x8 kf[4];
                for (int ni = 0; ni < 4; ++ni)
                    kf[ni] = *(const bf16x8*)(const void*)(
                        Ksm + (((ni * 16 + lm) * 128 + ks * 32 + lq * 8) ^ swz));
                for (int ni = 0; ni < 4; ++ni)
                    sacc[ni] = __builtin_amdgcn_mfma_f32_16x16x32_bf16(aq[ks], kf[ni], sacc[ni], 0, 0, 0);
            }

            // ---- causal mask: only the diagonal tile needs it ----
            if (j == t) {
                for (int ni = 0; ni < 4; ++ni) {
                    int col = ni * 16 + lm;
                    for (int r = 0; r < 4; ++r)
                        if (col > w * 16 + lq * 4 + r) sacc[ni][r] = NEG_BIG;
                }
            }

            // ---- online softmax (scale already folded into Q) ----
            for (int r = 0; r < 4; ++r) {
                float mx = fmaxf(fmaxf(sacc[0][r], sacc[1][r]),
                                 fmaxf(sacc[2][r], sacc[3][r]));
                for (int sft = 1; sft < 16; sft <<= 1) mx = fmaxf(mx, __shfl_xor(mx, sft));
                float mN = fmaxf(mrow[r], mx);
                float alpha = __expf(mrow[r] - mN);
                mrow[r] = mN;
                float psum = 0.f;
                int prow = w * 16 + lq * 4 + r;
                for (int ni = 0; ni < 4; ++ni) {
                    float pv = __expf(sacc[ni][r] - mN);
                    psum += pv;
                    Psm[prow * 64 + ((ni * 16 + lm) ^ ((prow & 7) << 3))] = f2bf(pv);
                }
                for (int sft = 1; sft < 16; sft <<= 1) psum += __shfl_xor(psum, sft);
                lrow[r] = lrow[r] * alpha + psum;
                for (int di = 0; di < 8; ++di) accO[di][r] *= alpha;
            }
            __syncthreads();

            // ---- PV: P(16x64) @ V(64x128) per wave ----
            for (int ks2 = 0; ks2 < 2; ++ks2) {
                bf16x8 pf = *(const bf16x8*)(const void*)(
                    Psm + (((w * 16 + lm) * 64 + ks2 * 32 + lq * 8) ^ swz));
                for (int di = 0; di < 8; ++di) {
                    bf16x8 vf = *(const bf16x8*)(const void*)(
                        Vsm + (((di * 16 + lm) * 64 + ks2 * 32 + lq * 8) ^ swz));
                    accO[di] = __builtin_amdgcn_mfma_f32_16x16x32_bf16(pf, vf, accO[di], 0, 0, 0);
                }
            }
        }

        // ---- epilogue ----
        for (int r = 0; r < 4; ++r) {
            float invl = 1.0f / fmaxf(lrow[r], 1e-30f);
            size_t rowg = (size_t)t * 64 + w * 16 + lq * 4 + r;
            for (int di = 0; di < 8; ++di)
                ctx[rowg * 4096 + h * 128 + di * 16 + lm] = f2bf(accO[di][r] * invl);
        }
    }
}

extern "C" void kernel_launch(void* const* d_in, const int* in_sizes, int n_in,
                              void* d_out, int out_size, void* d_ws, size_t ws_size,
                              hipStream_t stream) {
    const void* x   = d_in[0];
    const int* pos  = (const int*)d_in[1];
    const void* Wq  = d_in[2];
    const void* Wk  = d_in[3];
    const void* Wv  = d_in[4];
    const void* Wo  = d_in[5];
    const void* qs  = d_in[6];
    const void* ks  = d_in[7];

    if (ws_size < (size_t)145 * 1024 * 1024) return;
    char* ws = (char*)d_ws;
    u16* WqkvT = (u16*)ws;                                  // [6144][4096]   48 MiB
    u16* WoT   = (u16*)(ws + (size_t)48  * 1024 * 1024);    // [4096][4096]   32 MiB
    u16* qkv   = (u16*)(ws + (size_t)80  * 1024 * 1024);    // [2048][6144]   24 MiB
    u16* ctx   = qkv;                                       // aliases qkv (dead after VT/rms)
    u16* Qb    = (u16*)(ws + (size_t)104 * 1024 * 1024);    // [32][2048][128] 16 MiB
    u16* Kb    = (u16*)(ws + (size_t)120 * 1024 * 1024);    // [8][2048][128]   4 MiB
    u16* VTb   = (u16*)(ws + (size_t)124 * 1024 * 1024);    // [8][128][2048]   4 MiB
    u16* xb    = (u16*)(ws + (size_t)128 * 1024 * 1024);    // [2048][4096]    16 MiB
    int* flags = (int*)(ws + (size_t)144 * 1024 * 1024);
    u16* qsb   = (u16*)(ws + (size_t)144 * 1024 * 1024 + 1024);
    u16* ksb   = (u16*)(ws + (size_t)144 * 1024 * 1024 + 2048);

    dim3 b256(256);
    const int* flag  = flags;       // probed dtype
    const int* fzero = flags + 1;   // always 0

    detect_dtype<<<1, b256, 0, stream>>>((const u16*)Wq, flags);
    conv_bf16<<<8192, b256, 0, stream>>>(x,  xb,  (long)S_LEN * DMODEL, flag);
    conv_bf16<<<1,    b256, 0, stream>>>(qs, qsb, 128, flag);
    conv_bf16<<<1,    b256, 0, stream>>>(ks, ksb, 128, flag);

    // weight transposes into k-contiguous B^T layouts (bf16 out)
    transpose_any<<<dim3(128, 128, 1), b256, 0, stream>>>(Wq, 0, 4096, 0, WqkvT, 4096, 0, flag);
    transpose_any<<<dim3(32, 128, 1),  b256, 0, stream>>>(Wk, 0, 1024, 0, WqkvT + (size_t)4096 * 4096, 4096, 0, flag);
    transpose_any<<<dim3(32, 128, 1),  b256, 0, stream>>>(Wv, 0, 1024, 0, WqkvT + (size_t)5120 * 4096, 4096, 0, flag);
    transpose_any<<<dim3(128, 128, 1), b256, 0, stream>>>(Wo, 0, 4096, 0, WoT, 4096, 0, flag);

    // fused QKV projection: [2048][6144] bf16 (4-phase 256x256 pipelined GEMM)
    gemm_dp2_bf16<<<dim3(24, 8), dim3(512), 0, stream>>>(xb, WqkvT, qkv, 4096, NQKV);
    // RMSNorm + RoPE -> head-major Q (pre-scaled by 1/sqrt(128)) / K
    rms_rope<<<dim3(20480), b256, 0, stream>>>(qkv, pos, qsb, ksb, Qb, Kb);
    // V -> V^T per kv head ([8][128][2048]); qkv is bf16 -> force bf16 path
    transpose_any<<<dim3(4, 64, 8), b256, 0, stream>>>(qkv, 5120, NQKV, 128, VTb, 2048, (long)128 * 2048, fzero);
    // causal GQA flash attention: paired 64-row Q tiles -> ctx [2048][4096]
    flash_attn<<<dim3(16, 32), b256, 0, stream>>>(Qb, Kb, VTb, ctx);
    // output projection -> d_out as FP32 (4-phase 256x256 pipelined GEMM)
    gemm_dp2_f32<<<dim3(16, 8), dim3(512), 0, stream>>>(ctx, WoT, (float*)d_out, 4096, 4096);
}

// Round 5
// 533.965 us; speedup vs baseline: 1.3605x; 1.0513x over previous
//
#include <hip/hip_runtime.h>

#define S_LEN 2048
#define DMODEL 4096
#define NQKV 6144   // 32*128 + 8*128 + 8*128

typedef unsigned short u16;
typedef __attribute__((ext_vector_type(8))) short bf16x8;
typedef __attribute__((ext_vector_type(8))) unsigned short u16x8;
typedef __attribute__((ext_vector_type(4))) float f32x4;

#define NEG_BIG (-3.0e38f)

__device__ __forceinline__ float bf2f(u16 h) {
    union { unsigned u; float f; } c; c.u = ((unsigned)h) << 16; return c.f;
}
__device__ __forceinline__ u16 f2bf(float x) {
    union { float f; unsigned u; } c; c.f = x;
    return (u16)((c.u + 0x7fffu + ((c.u >> 16) & 1u)) >> 16);
}

// async global->LDS, 16B per lane; LDS dest = wave-uniform base + lane*16
__device__ __forceinline__ void gload16(const void* g, void* l) {
    __builtin_amdgcn_global_load_lds(
        (const __attribute__((address_space(1))) void*)g,
        (__attribute__((address_space(3))) void*)l, 16, 0, 0);
}

__device__ __forceinline__ void barfence() {
    asm volatile("" ::: "memory");
    __builtin_amdgcn_s_barrier();
    asm volatile("" ::: "memory");
}

#define MFMA16(d, av, bv) d = __builtin_amdgcn_mfma_f32_16x16x32_bf16(av, bv, d, 0, 0, 0)

// ------------- dtype probe: flag[0]=1 if `probe` is fp32-underlying ------------
__global__ __launch_bounds__(256) void detect_dtype(const u16* __restrict__ probe,
                                                    int* __restrict__ flags) {
    __shared__ int bad_s;
    if (threadIdx.x == 0) bad_s = 0;
    __syncthreads();
    int bad = 0;
    for (int i = threadIdx.x; i < 16384; i += 256) {
        float v = bf2f(probe[i]);
        if (!(fabsf(v) < 1e6f)) bad = 1;   // catches NaN too
    }
    if (bad) atomicOr(&bad_s, 1);
    __syncthreads();
    if (threadIdx.x == 0) { flags[0] = bad_s; flags[1] = 0; }
}

// ------------- convert (fp32 or bf16) -> bf16, flat ----------------------------
__global__ __launch_bounds__(256) void conv_bf16(const void* __restrict__ src,
                                                 u16* __restrict__ dst, long n,
                                                 const int* __restrict__ flag) {
    const bool f32 = (*flag != 0);
    long i = (long)blockIdx.x * 256 + threadIdx.x;
    long stride = (long)gridDim.x * 256;
    for (; i < n; i += stride) {
        float v = f32 ? ((const float*)src)[i] : bf2f(((const u16*)src)[i]);
        dst[i] = f2bf(v);
    }
}

// ------------- transpose (fp32-or-bf16 in, bf16 out): dst[c][r] = src[r][c] ----
__global__ __launch_bounds__(256) void transpose_any(
        const void* __restrict__ src, long base_off, long sld, long szoff,
        u16* __restrict__ dst, long dld, long dzoff,
        const int* __restrict__ flag) {
    __shared__ alignas(16) u16 tile[32][33];
    const bool f32 = (*flag != 0);
    u16* d = dst + (long)blockIdx.z * dzoff;
    long soff = base_off + (long)blockIdx.z * szoff;
    int c0 = blockIdx.x * 32, r0 = blockIdx.y * 32;
    int tx = threadIdx.x & 31, ty = threadIdx.x >> 5;   // 32x8
    for (int i = 0; i < 32; i += 8) {
        long idx = soff + (long)(r0 + ty + i) * sld + c0 + tx;
        float v = f32 ? ((const float*)src)[idx] : bf2f(((const u16*)src)[idx]);
        tile[ty + i][tx] = f2bf(v);
    }
    __syncthreads();
    for (int i = 0; i < 32; i += 8)
        d[(long)(c0 + ty + i) * dld + r0 + tx] = tile[tx][ty + i];
}

// ======== 4-phase 256x256 GEMM (m201-class): C[m][n] = sum_k A[m][k]*BT[n][k] ==
__device__ __forceinline__ void st_out(u16* C, size_t idx, float v)   { C[idx] = f2bf(v); }
__device__ __forceinline__ void st_out(float* C, size_t idx, float v) { C[idx] = v; }

template <typename OUT>
__device__ __forceinline__ void gemm_dp2_core(
        const u16* __restrict__ A, const u16* __restrict__ BT,
        OUT* __restrict__ C, int K, int ldc) {
    __shared__ alignas(16) u16 smem[65536];   // 2 bufs x (A 256x64 + B 256x64) = 128 KB
    const int tid = threadIdx.x;
    const int lane = tid & 63, wid = tid >> 6;
    const int wr = wid >> 2, wc = wid & 3;        // 2M x 4N waves
    const int lm = lane & 15, lq = lane >> 4;
    const int m0 = blockIdx.y * 256, n0 = blockIdx.x * 256;

    const int srow = tid >> 3;                       // row within chunk
    const int sgrp = (tid & 7) ^ (srow & 7);         // swizzled 8-u16 group
    const u16* aS = A  + (size_t)(m0 + srow) * K + sgrp * 8;
    const u16* bS = BT + (size_t)(n0 + srow) * K + sgrp * 8;
    u16* ldsA = smem + tid * 8;                      // + buf*32768 + c*4096
    u16* ldsB = smem + 16384 + tid * 8;

    auto stA = [&](int bufi, int c, int kti) {
        gload16(aS + (size_t)c * 64 * K + (size_t)kti * 64, ldsA + bufi * 32768 + c * 4096);
    };
    auto stB = [&](int bufi, int c, int kti) {
        gload16(bS + (size_t)c * 64 * K + (size_t)kti * 64, ldsB + bufi * 32768 + c * 4096);
    };
    auto rdA = [&](const u16* buf, int mi, int ks) {
        int row = wr * 128 + mi * 16 + lm;
        return *(const bf16x8*)(const void*)(buf + row * 64 + (((ks * 4 + lq) ^ (row & 7)) << 3));
    };
    auto rdB = [&](const u16* buf, int ni, int ks) {
        int row = wc * 64 + ni * 16 + lm;
        return *(const bf16x8*)(const void*)(buf + 16384 + row * 64 + (((ks * 4 + lq) ^ (row & 7)) << 3));
    };

    const int NK = K >> 6;
    stB(0, 0, 0); stB(0, 1, 0); stB(0, 2, 0); stB(0, 3, 0);
    stA(0, 0, 0); stA(0, 2, 0); stA(0, 1, 0); stA(0, 3, 0);

    f32x4 acc[8][4] = {};
    bf16x8 b[4][2], a[2][2];

#pragma unroll 2
    for (int kt = 0; kt < NK; ++kt) {
        const u16* buf = smem + (kt & 1) * 32768;
        const int nb = (kt & 1) ^ 1;
        const int kn = kt + 1;
        const bool more = kn < NK;

        // ---------- phase 0 ----------
        asm volatile("s_waitcnt vmcnt(2)" ::: "memory");
        barfence();
#pragma unroll
        for (int ni = 0; ni < 4; ++ni)
#pragma unroll
            for (int ks = 0; ks < 2; ++ks) b[ni][ks] = rdB(buf, ni, ks);
#pragma unroll
        for (int q = 0; q < 2; ++q)
#pragma unroll
            for (int ks = 0; ks < 2; ++ks) a[q][ks] = rdA(buf, q, ks);
        if (more) { stB(nb, 0, kn); stB(nb, 1, kn); }
        __builtin_amdgcn_s_setprio(1);
#pragma unroll
        for (int q = 0; q < 2; ++q)
#pragma unroll
            for (int ni = 0; ni < 4; ++ni)
#pragma unroll
                for (int ks = 0; ks < 2; ++ks) MFMA16(acc[q][ni], a[q][ks], b[ni][ks]);
        __builtin_amdgcn_s_setprio(0);

        // ---------- phase 1 ----------
#pragma unroll
        for (int q = 0; q < 2; ++q)
#pragma unroll
            for (int ks = 0; ks < 2; ++ks) a[q][ks] = rdA(buf, 2 + q, ks);
        if (more) { stB(nb, 2, kn); stB(nb, 3, kn); }
        __builtin_amdgcn_s_setprio(1);
#pragma unroll
        for (int q = 0; q < 2; ++q)
#pragma unroll
            for (int ni = 0; ni < 4; ++ni)
#pragma unroll
                for (int ks = 0; ks < 2; ++ks) MFMA16(acc[2 + q][ni], a[q][ks], b[ni][ks]);
        __builtin_amdgcn_s_setprio(0);

        // ---------- phase 2 ----------
        if (more) { asm volatile("s_waitcnt vmcnt(4)" ::: "memory"); }
        else      { asm volatile("s_waitcnt vmcnt(0)" ::: "memory"); }
        barfence();
#pragma unroll
        for (int q = 0; q < 2; ++q)
#pragma unroll
            for (int ks = 0; ks < 2; ++ks) a[q][ks] = rdA(buf, 4 + q, ks);
        if (more) { stA(nb, 0, kn); stA(nb, 2, kn); }
        __builtin_amdgcn_s_setprio(1);
#pragma unroll
        for (int q = 0; q < 2; ++q)
#pragma unroll
            for (int ni = 0; ni < 4; ++ni)
#pragma unroll
                for (int ks = 0; ks < 2; ++ks) MFMA16(acc[4 + q][ni], a[q][ks], b[ni][ks]);
        __builtin_amdgcn_s_setprio(0);

        // ---------- phase 3 ----------
#pragma unroll
        for (int q = 0; q < 2; ++q)
#pragma unroll
            for (int ks = 0; ks < 2; ++ks) a[q][ks] = rdA(buf, 6 + q, ks);
        if (more) { stA(nb, 1, kn); stA(nb, 3, kn); }
        __builtin_amdgcn_s_setprio(1);
#pragma unroll
        for (int q = 0; q < 2; ++q)
#pragma unroll
            for (int ni = 0; ni < 4; ++ni)
#pragma unroll
                for (int ks = 0; ks < 2; ++ks) MFMA16(acc[6 + q][ni], a[q][ks], b[ni][ks]);
        __builtin_amdgcn_s_setprio(0);
    }

#pragma unroll
    for (int mi = 0; mi < 8; ++mi)
#pragma unroll
        for (int ni = 0; ni < 4; ++ni) {
            int col  = n0 + wc * 64 + ni * 16 + lm;
            int rowb = m0 + wr * 128 + mi * 16 + lq * 4;
#pragma unroll
            for (int r = 0; r < 4; ++r)
                st_out(C, (size_t)(rowb + r) * ldc + col, acc[mi][ni][r]);
        }
}

__global__ __launch_bounds__(512, 2) void gemm_dp2_bf16(
        const u16* __restrict__ A, const u16* __restrict__ BT,
        u16* __restrict__ C, int K, int ldc) {
    gemm_dp2_core<u16>(A, BT, C, K, ldc);
}

// ======== 2-phase 128x256 GEMM (grid-doubling variant for Wo: 256 blocks) ======
// BK=64, 512 thr = 8 waves (4M x 2N), 32x128 out/wave, acc[2][8].
// Chunks: A0,A1 (64 rows each), B0..B3.  Issue ledger per tile:
// ph0 issues A0,A1,B0,B2 ; ph1 issues B1,B3  =>  waits vmcnt(2) @ph0, vmcnt(4) @ph1.
__global__ __launch_bounds__(512, 2) void gemm_dp3_f32(
        const u16* __restrict__ A, const u16* __restrict__ BT,
        float* __restrict__ C, int K, int ldc) {
    __shared__ alignas(16) u16 smem[49152];   // 2 bufs x (A 128x64 + B 256x64) = 96 KB
    const int tid = threadIdx.x;
    const int lane = tid & 63, wid = tid >> 6;
    const int wr = wid >> 1, wc = wid & 1;        // 4M x 2N waves
    const int lm = lane & 15, lq = lane >> 4;
    const int m0 = blockIdx.y * 128, n0 = blockIdx.x * 256;

    const int srow = tid >> 3;
    const int sgrp = (tid & 7) ^ (srow & 7);
    const u16* aS = A  + (size_t)(m0 + srow) * K + sgrp * 8;
    const u16* bS = BT + (size_t)(n0 + srow) * K + sgrp * 8;
    u16* ldsA = smem + tid * 8;                   // + buf*24576 + c*4096
    u16* ldsB = smem + 8192 + tid * 8;

    auto stA = [&](int bufi, int c, int kti) {
        gload16(aS + (size_t)c * 64 * K + (size_t)kti * 64, ldsA + bufi * 24576 + c * 4096);
    };
    auto stB = [&](int bufi, int c, int kti) {
        gload16(bS + (size_t)c * 64 * K + (size_t)kti * 64, ldsB + bufi * 24576 + c * 4096);
    };
    auto rdA = [&](const u16* buf, int mi, int ks) {
        int row = wr * 32 + mi * 16 + lm;
        return *(const bf16x8*)(const void*)(buf + row * 64 + (((ks * 4 + lq) ^ (row & 7)) << 3));
    };
    auto rdB = [&](const u16* buf, int ni, int ks) {
        int row = wc * 128 + ni * 16 + lm;
        return *(const bf16x8*)(const void*)(buf + 8192 + row * 64 + (((ks * 4 + lq) ^ (row & 7)) << 3));
    };

    const int NK = K >> 6;
    // prologue (tile 0): ph0-needs first, then B1,B3 (newest 2)
    stA(0, 0, 0); stA(0, 1, 0); stB(0, 0, 0); stB(0, 2, 0);
    stB(0, 1, 0); stB(0, 3, 0);

    f32x4 acc[2][8] = {};
    bf16x8 a[2][2], b[4][2];

#pragma unroll 2
    for (int kt = 0; kt < NK; ++kt) {
        const u16* buf = smem + (kt & 1) * 24576;
        const int nb = (kt & 1) ^ 1;
        const int kn = kt + 1;
        const bool more = kn < NK;

        // ---------- phase 0: A all + B chunk 2wc (frags ni 0..3) ----------
        asm volatile("s_waitcnt vmcnt(2)" ::: "memory");   // A0,A1,B0,B2 landed
        barfence();
#pragma unroll
        for (int mi = 0; mi < 2; ++mi)
#pragma unroll
            for (int ks = 0; ks < 2; ++ks) a[mi][ks] = rdA(buf, mi, ks);
#pragma unroll
        for (int ni = 0; ni < 4; ++ni)
#pragma unroll
            for (int ks = 0; ks < 2; ++ks) b[ni][ks] = rdB(buf, ni, ks);
        if (more) { stA(nb, 0, kn); stA(nb, 1, kn); stB(nb, 0, kn); stB(nb, 2, kn); }
        __builtin_amdgcn_s_setprio(1);
#pragma unroll
        for (int mi = 0; mi < 2; ++mi)
#pragma unroll
            for (int ni = 0; ni < 4; ++ni)
#pragma unroll
                for (int ks = 0; ks < 2; ++ks) MFMA16(acc[mi][ni], a[mi][ks], b[ni][ks]);
        __builtin_amdgcn_s_setprio(0);

        // ---------- phase 1: B chunk 2wc+1 (frags ni 4..7) ----------
        if (more) { asm volatile("s_waitcnt vmcnt(4)" ::: "memory"); }
        else      { asm volatile("s_waitcnt vmcnt(0)" ::: "memory"); }
        barfence();
#pragma unroll
        for (int ni = 0; ni < 4; ++ni)
#pragma unroll
            for (int ks = 0; ks < 2; ++ks) b[ni][ks] = rdB(buf, 4 + ni, ks);
        if (more) { stB(nb, 1, kn); stB(nb, 3, kn); }
        __builtin_amdgcn_s_setprio(1);
#pragma unroll
        for (int mi = 0; mi < 2; ++mi)
#pragma unroll
            for (int ni = 0; ni < 4; ++ni)
#pragma unroll
                for (int ks = 0; ks < 2; ++ks) MFMA16(acc[mi][4 + ni], a[mi][ks], b[ni][ks]);
        __builtin_amdgcn_s_setprio(0);
    }

#pragma unroll
    for (int mi = 0; mi < 2; ++mi)
#pragma unroll
        for (int ni = 0; ni < 8; ++ni) {
            int col  = n0 + wc * 128 + ni * 16 + lm;
            int rowb = m0 + wr * 32 + mi * 16 + lq * 4;
#pragma unroll
            for (int r = 0; r < 4; ++r)
                C[(size_t)(rowb + r) * ldc + col] = acc[mi][ni][r];
        }
}

// ---------------- RMSNorm + RoPE on q (32 heads) and k (8 heads) ---------------
// NOTE: folds 1/sqrt(128) attention scale into Q (linear, commutes with RoPE)
__global__ __launch_bounds__(256) void rms_rope(
        const u16* __restrict__ qkv, const int* __restrict__ pos,
        const u16* __restrict__ qs, const u16* __restrict__ kscale,
        u16* __restrict__ Qb, u16* __restrict__ Kb) {
    int w = threadIdx.x >> 6, lane = threadIdx.x & 63;
    int task = blockIdx.x * 4 + w;            // task = h*2048 + row, h in [0,40)
    int h = task >> 11, row = task & 2047;
    int base = (h < 32) ? h * 128 : 4096 + (h - 32) * 128;
    const u16* src = qkv + (size_t)row * NQKV + base;
    float t0 = bf2f(src[lane]), t1 = bf2f(src[lane + 64]);
    float ss = t0 * t0 + t1 * t1;
    for (int m = 1; m < 64; m <<= 1) ss += __shfl_xor(ss, m);
    float inv = rsqrtf(ss * (1.0f / 128.0f) + 1e-6f);
    const u16* sc = (h < 32) ? qs : kscale;
    float n0 = t0 * inv * bf2f(sc[lane]);
    float n1 = t1 * inv * bf2f(sc[lane + 64]);
    float p = (float)pos[row];
    float ang = p * __expf(-(float)lane * (9.210340371976184f / 64.0f));  // 10000^(-lane/64)
    float c = cosf(ang), s = sinf(ang);
    float o0 = n0 * c - n1 * s;
    float o1 = n1 * c + n0 * s;
    float mul = (h < 32) ? 0.08838834764831845f : 1.0f;   // 1/sqrt(128) folded into Q
    u16* dst = (h < 32) ? (Qb + ((size_t)h * S_LEN + row) * 128)
                        : (Kb + ((size_t)(h - 32) * S_LEN + row) * 128);
    dst[lane] = f2bf(o0 * mul);
    dst[lane + 64] = f2bf(o1 * mul);
}

// ---------------- flash attention v3: dbuf K/V + counted vmcnt -----------------
// block x in [0,16) handles Q-tiles t=x and t=31-x  => exactly 33 KV-iters/block
// LDS 72 KB: K0,K1 [64][128], V0,V1 [128][64], P [64][64] (all XOR-swizzled).
// Per iter: stage j+1 -> buf[(j+1)&1]; wait vmcnt(8) (tile j landed, j+1 in
// flight); raw s_barrier (NOT __syncthreads - that drains vmcnt to 0).
__global__ __launch_bounds__(256, 2) void flash_attn(
        const u16* __restrict__ Qb, const u16* __restrict__ Kb,
        const u16* __restrict__ VTb, u16* __restrict__ ctx) {
    const int h = blockIdx.y, kvh = h >> 2;
    const int tid = threadIdx.x, lane = tid & 63, w = tid >> 6;
    const int lm = lane & 15, lq = lane >> 4;
    const int swz = (lm & 7) << 3;                 // read-side XOR (u16 units)
    __shared__ alignas(16) u16 smem[36864];        // 72 KB
    u16* Psm = smem + 32768;                       // [64][64] swizzled
    const u16* Kh = Kb + (size_t)kvh * S_LEN * 128;
    const u16* Vh = VTb + (size_t)kvh * 128 * S_LEN;

    auto stageK = [&](int j) {   // K(j) -> Kbuf[j&1] = smem + (j&1)*8192
        for (int i = 0; i < 4; ++i) {
            int g = i * 256 + tid;
            int row = g >> 4, s = g & 15;
            int sp = (s & 8) | ((s ^ row) & 7);
            gload16(Kh + (size_t)(j * 64 + row) * 128 + sp * 8,
                    smem + (j & 1) * 8192 + (size_t)(i * 256 + w * 64) * 8);
        }
    };
    auto stageV = [&](int j) {   // V^T(j) -> Vbuf[j&1] = smem + 16384 + (j&1)*8192
        for (int i = 0; i < 4; ++i) {
            int g = i * 256 + tid;
            int d = g >> 3, s = g & 7;
            int sp = s ^ (d & 7);
            gload16(Vh + (size_t)d * S_LEN + j * 64 + sp * 8,
                    smem + 16384 + (j & 1) * 8192 + (size_t)(i * 256 + w * 64) * 8);
        }
    };

    for (int pass = 0; pass < 2; ++pass) {
        const int t = pass ? (31 - blockIdx.x) : blockIdx.x;
        const u16* Qh = Qb + ((size_t)h * S_LEN + (size_t)t * 64) * 128;

        barfence();   // prev pass LDS reads done
        // ---- stage 64x128 Q tile (swizzled) into K0 area ----
        for (int i = 0; i < 4; ++i) {
            int g = i * 256 + tid;
            int row = g >> 4, s = g & 15;
            int sp = (s & 8) | ((s ^ row) & 7);
            gload16(Qh + (size_t)row * 128 + sp * 8,
                    smem + (size_t)(i * 256 + w * 64) * 8);
        }
        asm volatile("s_waitcnt vmcnt(0)" ::: "memory");
        barfence();
        bf16x8 aq[4];
        for (int ks = 0; ks < 4; ++ks)
            aq[ks] = *(const bf16x8*)(const void*)(
                smem + (((w * 16 + lm) * 128 + ks * 32 + lq * 8) ^ swz));
        asm volatile("s_waitcnt lgkmcnt(0)" ::: "memory");
        barfence();   // all waves' Q reads done before K(0) overwrites K0
        stageK(0); stageV(0);

        float mrow[4], lrow[4];
        f32x4 accO[8];
        const f32x4 zero = {0.f, 0.f, 0.f, 0.f};
        for (int r = 0; r < 4; ++r) { mrow[r] = NEG_BIG; lrow[r] = 0.f; }
        for (int di = 0; di < 8; ++di) accO[di] = zero;

        for (int j = 0; j <= t; ++j) {
            const u16* Kj = smem + (j & 1) * 8192;
            const u16* Vj = smem + 16384 + (j & 1) * 8192;
            if (j < t) {
                stageK(j + 1); stageV(j + 1);
                asm volatile("s_waitcnt vmcnt(8)" ::: "memory");   // tile j landed
            } else {
                asm volatile("s_waitcnt vmcnt(0)" ::: "memory");
            }
            barfence();   // staged data visible to all waves

            // ---- QK^T: 16 rows x 64 cols per wave ----
            f32x4 sacc[4] = {};
            for (int ks = 0; ks < 4; ++ks) {
                bf16x8 kf[4];
                for (int ni = 0; ni < 4; ++ni)
                    kf[ni] = *(const bf16x8*)(const void*)(
                        Kj + (((ni * 16 + lm) * 128 + ks * 32 + lq * 8) ^ swz));
                for (int ni = 0; ni < 4; ++ni)
                    sacc[ni] = __builtin_amdgcn_mfma_f32_16x16x32_bf16(aq[ks], kf[ni], sacc[ni], 0, 0, 0);
            }

            // ---- causal mask: only the diagonal tile needs it ----
            if (j == t) {
                for (int ni = 0; ni < 4; ++ni) {
                    int col = ni * 16 + lm;
                    for (int r = 0; r < 4; ++r)
                        if (col > w * 16 + lq * 4 + r) sacc[ni][r] = NEG_BIG;
                }
            }

            // ---- online softmax (scale already folded into Q) ----
            for (int r = 0; r < 4; ++r) {
                float mx = fmaxf(fmaxf(sacc[0][r], sacc[1][r]),
                                 fmaxf(sacc[2][r], sacc[3][r]));
                for (int sft = 1; sft < 16; sft <<= 1) mx = fmaxf(mx, __shfl_xor(mx, sft));
                float mN = fmaxf(mrow[r], mx);
                float alpha = __expf(mrow[r] - mN);
                mrow[r] = mN;
                float psum = 0.f;
                int prow = w * 16 + lq * 4 + r;
                for (int ni = 0; ni < 4; ++ni) {
                    float pv = __expf(sacc[ni][r] - mN);
                    psum += pv;
                    Psm[prow * 64 + ((ni * 16 + lm) ^ ((prow & 7) << 3))] = f2bf(pv);
                }
                for (int sft = 1; sft < 16; sft <<= 1) psum += __shfl_xor(psum, sft);
                lrow[r] = lrow[r] * alpha + psum;
                for (int di = 0; di < 8; ++di) accO[di][r] *= alpha;
            }
            asm volatile("s_waitcnt lgkmcnt(0)" ::: "memory");   // P writes drained
            barfence();   // P visible

            // ---- PV: P(16x64) @ V(64x128) per wave ----
            for (int ks2 = 0; ks2 < 2; ++ks2) {
                bf16x8 pf = *(const bf16x8*)(const void*)(
                    Psm + (((w * 16 + lm) * 64 + ks2 * 32 + lq * 8) ^ swz));
                for (int di = 0; di < 8; ++di) {
                    bf16x8 vf = *(const bf16x8*)(const void*)(
                        Vj + (((di * 16 + lm) * 64 + ks2 * 32 + lq * 8) ^ swz));
                    accO[di] = __builtin_amdgcn_mfma_f32_16x16x32_bf16(pf, vf, accO[di], 0, 0, 0);
                }
            }
            barfence();   // PV reads done before next iter overwrites buf[(j+2)&1]
        }

        // ---- epilogue ----
        for (int r = 0; r < 4; ++r) {
            float invl = 1.0f / fmaxf(lrow[r], 1e-30f);
            size_t rowg = (size_t)t * 64 + w * 16 + lq * 4 + r;
            for (int di = 0; di < 8; ++di)
                ctx[rowg * 4096 + h * 128 + di * 16 + lm] = f2bf(accO[di][r] * invl);
        }
    }
}

extern "C" void kernel_launch(void* const* d_in, const int* in_sizes, int n_in,
                              void* d_out, int out_size, void* d_ws, size_t ws_size,
                              hipStream_t stream) {
    const void* x   = d_in[0];
    const int* pos  = (const int*)d_in[1];
    const void* Wq  = d_in[2];
    const void* Wk  = d_in[3];
    const void* Wv  = d_in[4];
    const void* Wo  = d_in[5];
    const void* qs  = d_in[6];
    const void* ks  = d_in[7];

    if (ws_size < (size_t)145 * 1024 * 1024) return;
    char* ws = (char*)d_ws;
    u16* WqkvT = (u16*)ws;                                  // [6144][4096]   48 MiB
    u16* WoT   = (u16*)(ws + (size_t)48  * 1024 * 1024);    // [4096][4096]   32 MiB
    u16* qkv   = (u16*)(ws + (size_t)80  * 1024 * 1024);    // [2048][6144]   24 MiB
    u16* ctx   = qkv;                                       // aliases qkv (dead after VT/rms)
    u16* Qb    = (u16*)(ws + (size_t)104 * 1024 * 1024);    // [32][2048][128] 16 MiB
    u16* Kb    = (u16*)(ws + (size_t)120 * 1024 * 1024);    // [8][2048][128]   4 MiB
    u16* VTb   = (u16*)(ws + (size_t)124 * 1024 * 1024);    // [8][128][2048]   4 MiB
    u16* xb    = (u16*)(ws + (size_t)128 * 1024 * 1024);    // [2048][4096]    16 MiB
    int* flags = (int*)(ws + (size_t)144 * 1024 * 1024);
    u16* qsb   = (u16*)(ws + (size_t)144 * 1024 * 1024 + 1024);
    u16* ksb   = (u16*)(ws + (size_t)144 * 1024 * 1024 + 2048);

    dim3 b256(256);
    const int* flag  = flags;       // probed dtype
    const int* fzero = flags + 1;   // always 0

    detect_dtype<<<1, b256, 0, stream>>>((const u16*)Wq, flags);
    conv_bf16<<<8192, b256, 0, stream>>>(x,  xb,  (long)S_LEN * DMODEL, flag);
    conv_bf16<<<1,    b256, 0, stream>>>(qs, qsb, 128, flag);
    conv_bf16<<<1,    b256, 0, stream>>>(ks, ksb, 128, flag);

    // weight transposes into k-contiguous B^T layouts (bf16 out)
    transpose_any<<<dim3(128, 128, 1), b256, 0, stream>>>(Wq, 0, 4096, 0, WqkvT, 4096, 0, flag);
    transpose_any<<<dim3(32, 128, 1),  b256, 0, stream>>>(Wk, 0, 1024, 0, WqkvT + (size_t)4096 * 4096, 4096, 0, flag);
    transpose_any<<<dim3(32, 128, 1),  b256, 0, stream>>>(Wv, 0, 1024, 0, WqkvT + (size_t)5120 * 4096, 4096, 0, flag);
    transpose_any<<<dim3(128, 128, 1), b256, 0, stream>>>(Wo, 0, 4096, 0, WoT, 4096, 0, flag);

    // fused QKV projection: [2048][6144] bf16 (4-phase 256x256 pipelined GEMM)
    gemm_dp2_bf16<<<dim3(24, 8), dim3(512), 0, stream>>>(xb, WqkvT, qkv, 4096, NQKV);
    // RMSNorm + RoPE -> head-major Q (pre-scaled by 1/sqrt(128)) / K
    rms_rope<<<dim3(20480), b256, 0, stream>>>(qkv, pos, qsb, ksb, Qb, Kb);
    // V -> V^T per kv head ([8][128][2048]); qkv is bf16 -> force bf16 path
    transpose_any<<<dim3(4, 64, 8), b256, 0, stream>>>(qkv, 5120, NQKV, 128, VTb, 2048, (long)128 * 2048, fzero);
    // causal GQA flash attention: paired 64-row Q tiles -> ctx [2048][4096]
    flash_attn<<<dim3(16, 32), b256, 0, stream>>>(Qb, Kb, VTb, ctx);
    // output projection -> d_out as FP32 (2-phase 128x256 GEMM, grid = 256 blocks)
    gemm_dp3_f32<<<dim3(16, 16), dim3(512), 0, stream>>>(ctx, WoT, (float*)d_out, 4096, 4096);
}